// Round 5
// baseline (418.150 us; speedup 1.0000x reference)
//
#include <hip/hip_runtime.h>
#include <hip/hip_bf16.h>
#include <stdint.h>

// N=4096, IN=512, OUT=64, H=8. Inputs (fp32): x[N*IN], adj int32[N*N],
// W[H*IN*OUT], a1[H*OUT], a2[H*OUT]. Output fp32[N, H*OUT]  (reference dtype = float32).
// ws layout: bitsT u64[64*N] (2MB) | Wh f32[H*N*64] (8MB) | f1 f32[H*N] | f2 f32[H*N]

constexpr int N_   = 4096;
constexpr int IN_  = 512;
constexpr int OUT_ = 64;
constexpr int H_   = 8;
constexpr float ALPHA_ = 0.2f;

// ---------- kernel 1: pack adj -> transposed bitmask bitsT[c*N + n], bit i of word = adj[n][c*64+i]
__global__ __launch_bounds__(256) void pack_adj(const int* __restrict__ adj,
                                                unsigned long long* __restrict__ bitsT) {
    size_t g = (size_t)blockIdx.x * 256 + threadIdx.x;   // g = n*4096 + m
    int v = adj[g];
    unsigned long long m = __ballot(v != 0);
    if ((threadIdx.x & 63) == 0) {
        int n = (int)(g >> 12);
        int c = (int)((g >> 6) & 63);
        bitsT[(size_t)c * N_ + n] = m;
    }
}

// ---------- kernel 2: Wh[h,n,o] = sum_k x[n,k] * W[h,k,o]  (fp32, 64x64 tile per block)
__global__ __launch_bounds__(256) void wh_gemm(const float* __restrict__ x,
                                               const float* __restrict__ W,
                                               float* __restrict__ Wh) {
    __shared__ float xT[32 * 68];   // [kk][r], padded
    __shared__ float Wl[32 * 68];   // [kk][c], padded
    const int t  = threadIdx.x;
    const int h  = blockIdx.y;
    const int n0 = blockIdx.x * 64;
    const int tr = t >> 4, tc = t & 15;

    float acc[4][4];
#pragma unroll
    for (int i = 0; i < 4; i++)
#pragma unroll
        for (int j = 0; j < 4; j++) acc[i][j] = 0.f;

    const int xr = t >> 2, xk0 = (t & 3) * 8;
    const int wk = t >> 3, wc0 = (t & 7) * 8;
    const float* xg = x + (size_t)(n0 + xr) * IN_ + xk0;
    const float* Wg = W + (size_t)h * IN_ * OUT_ + (size_t)wk * OUT_ + wc0;

    for (int k0 = 0; k0 < IN_; k0 += 32) {
        __syncthreads();
        float4 ux0 = *(const float4*)(xg + k0);
        float4 ux1 = *(const float4*)(xg + k0 + 4);
        float4 uw0 = *(const float4*)(Wg + (size_t)k0 * OUT_);
        float4 uw1 = *(const float4*)(Wg + (size_t)k0 * OUT_ + 4);
        xT[(xk0 + 0) * 68 + xr] = ux0.x;
        xT[(xk0 + 1) * 68 + xr] = ux0.y;
        xT[(xk0 + 2) * 68 + xr] = ux0.z;
        xT[(xk0 + 3) * 68 + xr] = ux0.w;
        xT[(xk0 + 4) * 68 + xr] = ux1.x;
        xT[(xk0 + 5) * 68 + xr] = ux1.y;
        xT[(xk0 + 6) * 68 + xr] = ux1.z;
        xT[(xk0 + 7) * 68 + xr] = ux1.w;
        *(float4*)&Wl[wk * 68 + wc0]     = uw0;
        *(float4*)&Wl[wk * 68 + wc0 + 4] = uw1;
        __syncthreads();
#pragma unroll 8
        for (int kk = 0; kk < 32; kk++) {
            float4 a = *(const float4*)&xT[kk * 68 + tr * 4];
            float4 b = *(const float4*)&Wl[kk * 68 + tc * 4];
            acc[0][0] += a.x * b.x; acc[0][1] += a.x * b.y; acc[0][2] += a.x * b.z; acc[0][3] += a.x * b.w;
            acc[1][0] += a.y * b.x; acc[1][1] += a.y * b.y; acc[1][2] += a.y * b.z; acc[1][3] += a.y * b.w;
            acc[2][0] += a.z * b.x; acc[2][1] += a.z * b.y; acc[2][2] += a.z * b.z; acc[2][3] += a.z * b.w;
            acc[3][0] += a.w * b.x; acc[3][1] += a.w * b.y; acc[3][2] += a.w * b.z; acc[3][3] += a.w * b.w;
        }
    }
    float* og = Wh + ((size_t)h * N_ + n0) * OUT_;
#pragma unroll
    for (int i = 0; i < 4; i++) {
        float4 v = make_float4(acc[i][0], acc[i][1], acc[i][2], acc[i][3]);
        *(float4*)&og[(tr * 4 + i) * OUT_ + tc * 4] = v;
    }
}

// ---------- kernel 3: f1[h,n] = Wh[h,n,:] . a1[h,:], f2 likewise. One wave per row.
__global__ __launch_bounds__(256) void f_vec(const float* __restrict__ Wh,
                                             const float* __restrict__ a1,
                                             const float* __restrict__ a2,
                                             float* __restrict__ f1,
                                             float* __restrict__ f2) {
    size_t g = (size_t)blockIdx.x * 256 + threadIdx.x;
    int lane = (int)(g & 63);
    size_t row = g >> 6;               // h*N + n
    int h = (int)(row >> 12);
    float w = Wh[row * OUT_ + lane];
    float v1 = w * a1[h * OUT_ + lane];
    float v2 = w * a2[h * OUT_ + lane];
#pragma unroll
    for (int s = 32; s > 0; s >>= 1) {
        v1 += __shfl_xor(v1, s, 64);
        v2 += __shfl_xor(v2, s, 64);
    }
    if (lane == 0) { f1[row] = v1; f2[row] = v2; }
}

// ---------- kernel 4: masked softmax (unnormalized) + PV, 64 rows per block, one head per block
__global__ __launch_bounds__(256) void gat_main(const unsigned long long* __restrict__ bitsT,
                                                const float* __restrict__ Wh,
                                                const float* __restrict__ f1,
                                                const float* __restrict__ f2,
                                                float* __restrict__ out) {
    __shared__ float f2s[N_];          // 16 KB
    __shared__ float Ps[64 * 68];      // P tile [mm][r], padded (transposed)
    __shared__ float Wt[64 * 68];      // Wh tile [mm][c], padded
    __shared__ float Ls[64];
    const int t  = threadIdx.x;
    const int h  = blockIdx.y;
    const int n0 = blockIdx.x * 64;
    const int mm = t & 63, rg = t >> 6;
    const int tr = t >> 4, tc = t & 15;

    {   // stage f2[h,:] (contiguous 16 KB)
        const float4* f2g = (const float4*)(f2 + (size_t)h * N_);
#pragma unroll
        for (int j = 0; j < 4; j++) ((float4*)f2s)[t + j * 256] = f2g[t + j * 256];
    }
    float f1r[16];
#pragma unroll
    for (int i = 0; i < 16; i++) f1r[i] = f1[(size_t)h * N_ + n0 + rg * 16 + i];
    float Lp[16];
#pragma unroll
    for (int i = 0; i < 16; i++) Lp[i] = 0.f;
    float acc[4][4];
#pragma unroll
    for (int i = 0; i < 4; i++)
#pragma unroll
        for (int j = 0; j < 4; j++) acc[i][j] = 0.f;

    const float4* whg = (const float4*)(Wh + (size_t)h * N_ * OUT_);

    for (int chunk = 0; chunk < 64; chunk++) {
        const int m0 = chunk * 64;
        __syncthreads();   // previous phase B done with Ps/Wt; covers f2s on iter 0
        // stage Wh[h, m0:m0+64, :] (contiguous 16 KB) into Wt
#pragma unroll
        for (int j = 0; j < 4; j++) {
            int f = t + j * 256;                       // float4 index in tile
            float4 v = whg[m0 * 16 + f];
            *(float4*)&Wt[(f >> 4) * 68 + (f & 15) * 4] = v;
        }
        // phase A: P[mm][r] = mask ? exp(leakyrelu(f1[r]+f2[m0+mm])) : 0
        const float f2v = f2s[m0 + mm];
        const unsigned long long* brow = bitsT + (size_t)chunk * N_ + n0 + rg * 16;
#pragma unroll
        for (int i4 = 0; i4 < 4; i4++) {
            float pv[4];
#pragma unroll
            for (int j = 0; j < 4; j++) {
                int i = i4 * 4 + j;
                unsigned long long w = brow[i];
                float s = f1r[i] + f2v;
                float e = fmaxf(s, ALPHA_ * s);
                float p = ((w >> mm) & 1ull) ? __expf(e) : 0.f;
                pv[j] = p;
                Lp[i] += p;
            }
            *(float4*)&Ps[mm * 68 + rg * 16 + i4 * 4] = make_float4(pv[0], pv[1], pv[2], pv[3]);
        }
        __syncthreads();   // Ps + Wt visible
        // phase B: acc[r][c] += sum_mm P[mm][r] * Wt[mm][c]
#pragma unroll 8
        for (int k = 0; k < 64; k++) {
            float4 a = *(const float4*)&Ps[k * 68 + tr * 4];
            float4 b = *(const float4*)&Wt[k * 68 + tc * 4];
            acc[0][0] += a.x * b.x; acc[0][1] += a.x * b.y; acc[0][2] += a.x * b.z; acc[0][3] += a.x * b.w;
            acc[1][0] += a.y * b.x; acc[1][1] += a.y * b.y; acc[1][2] += a.y * b.z; acc[1][3] += a.y * b.w;
            acc[2][0] += a.z * b.x; acc[2][1] += a.z * b.y; acc[2][2] += a.z * b.z; acc[2][3] += a.z * b.w;
            acc[3][0] += a.w * b.x; acc[3][1] += a.w * b.y; acc[3][2] += a.w * b.z; acc[3][3] += a.w * b.w;
        }
    }
    // reduce Lp over the wave's 64 lanes (each lane holds one mm-column's partial)
#pragma unroll
    for (int i = 0; i < 16; i++) {
        float v = Lp[i];
        v += __shfl_xor(v, 1, 64);  v += __shfl_xor(v, 2, 64);  v += __shfl_xor(v, 4, 64);
        v += __shfl_xor(v, 8, 64);  v += __shfl_xor(v, 16, 64); v += __shfl_xor(v, 32, 64);
        if (mm == 0) Ls[rg * 16 + i] = v;
    }
    __syncthreads();
    // epilogue: normalize + fp32 store. out[n, h*64+c]
#pragma unroll
    for (int i = 0; i < 4; i++) {
        int r = tr * 4 + i;
        float invL = 1.0f / Ls[r];
        float4 st = make_float4(acc[i][0] * invL, acc[i][1] * invL,
                                acc[i][2] * invL, acc[i][3] * invL);
        *(float4*)(out + (size_t)(n0 + r) * (H_ * OUT_) + h * OUT_ + tc * 4) = st;
    }
}

extern "C" void kernel_launch(void* const* d_in, const int* in_sizes, int n_in,
                              void* d_out, int out_size, void* d_ws, size_t ws_size,
                              hipStream_t stream) {
    // Bind inputs by element count (robust to permutation); fall back to dict order.
    const float* x   = nullptr;
    const int*   adj = nullptr;
    const float* W   = nullptr;
    const float* a1  = nullptr;
    const float* a2  = nullptr;
    for (int i = 0; i < n_in; i++) {
        long long sz = in_sizes[i];
        if      (sz == (long long)N_ * IN_)        x   = (const float*)d_in[i];
        else if (sz == (long long)N_ * N_)         adj = (const int*)d_in[i];
        else if (sz == (long long)H_ * IN_ * OUT_) W   = (const float*)d_in[i];
        else if (sz == (long long)H_ * OUT_) {
            if (!a1) a1 = (const float*)d_in[i];
            else     a2 = (const float*)d_in[i];
        }
    }
    if (!x)   x   = (const float*)d_in[0];
    if (!adj) adj = (const int*)d_in[1];
    if (!W)   W   = (const float*)d_in[2];
    if (!a1)  a1  = (const float*)d_in[3];
    if (!a2)  a2  = (const float*)d_in[4];
    float* out = (float*)d_out;

    char* ws = (char*)d_ws;
    unsigned long long* bitsT = (unsigned long long*)ws;                 // 2 MB
    float* Wh = (float*)(ws + (2u << 20));                               // 8 MB
    float* f1 = (float*)(ws + (10u << 20));                              // 128 KB
    float* f2 = (float*)(ws + (10u << 20) + (128u << 10));               // 128 KB

    pack_adj<<<(N_ * (size_t)N_) / 256, 256, 0, stream>>>(adj, bitsT);
    wh_gemm<<<dim3(N_ / 64, H_), 256, 0, stream>>>(x, W, Wh);
    f_vec<<<(H_ * N_ * 64) / 256, 256, 0, stream>>>(Wh, a1, a2, f1, f2);
    gat_main<<<dim3(N_ / 64, H_), 256, 0, stream>>>(bitsT, Wh, f1, f2, out);
}

// Round 6
// 261.280 us; speedup vs baseline: 1.6004x; 1.6004x over previous
//
#include <hip/hip_runtime.h>
#include <hip/hip_bf16.h>
#include <stdint.h>

// N=4096, IN=512, OUT=64, H=8. Inputs (fp32): x[N*IN], adj int32[N*N],
// W[H*IN*OUT], a1[H*OUT], a2[H*OUT]. Output fp32[N, H*OUT].
// ws: bitsT u64[64*N] (2MB) | Wh f32 (8MB) | f1 (128KB) | f2 (128KB)
//     | WhhT bf16[H][64][4096] (4MB) | WhlT bf16 (4MB)   => 18.25 MB total

constexpr int N_   = 4096;
constexpr int IN_  = 512;
constexpr int OUT_ = 64;
constexpr int H_   = 8;
constexpr float ALPHA_ = 0.2f;

typedef __attribute__((ext_vector_type(8))) short short8;   // 8 bf16 (4 VGPRs)
typedef __attribute__((ext_vector_type(4))) float f32x4;

// RNE-round two floats to bf16, return packed pair + the rounded floats
__device__ __forceinline__ uint32_t rne_pack2(float a, float b, float& ra, float& rb) {
    uint32_t ua = __float_as_uint(a); ua += 0x7fffu + ((ua >> 16) & 1u); ua >>= 16;
    uint32_t ub = __float_as_uint(b); ub += 0x7fffu + ((ub >> 16) & 1u); ub >>= 16;
    ra = __uint_as_float(ua << 16);
    rb = __uint_as_float(ub << 16);
    return ua | (ub << 16);
}

// ---------- kernel 1: pack adj -> transposed bitmask bitsT[c*N + n], bit i = adj[n][c*64+i]
__global__ __launch_bounds__(256) void pack_adj(const int* __restrict__ adj,
                                                unsigned long long* __restrict__ bitsT) {
    size_t g = (size_t)blockIdx.x * 256 + threadIdx.x;   // g = n*4096 + m
    int v = adj[g];
    unsigned long long m = __ballot(v != 0);
    if ((threadIdx.x & 63) == 0) {
        int n = (int)(g >> 12);
        int c = (int)((g >> 6) & 63);
        bitsT[(size_t)c * N_ + n] = m;
    }
}

// ---------- kernel 2: Wh[h,n,o] = sum_k x[n,k] * W[h,k,o]  (fp32, 64x64 tile per block)
__global__ __launch_bounds__(256) void wh_gemm(const float* __restrict__ x,
                                               const float* __restrict__ W,
                                               float* __restrict__ Wh) {
    __shared__ float xT[32 * 68];
    __shared__ float Wl[32 * 68];
    const int t  = threadIdx.x;
    const int h  = blockIdx.y;
    const int n0 = blockIdx.x * 64;
    const int tr = t >> 4, tc = t & 15;

    float acc[4][4];
#pragma unroll
    for (int i = 0; i < 4; i++)
#pragma unroll
        for (int j = 0; j < 4; j++) acc[i][j] = 0.f;

    const int xr = t >> 2, xk0 = (t & 3) * 8;
    const int wk = t >> 3, wc0 = (t & 7) * 8;
    const float* xg = x + (size_t)(n0 + xr) * IN_ + xk0;
    const float* Wg = W + (size_t)h * IN_ * OUT_ + (size_t)wk * OUT_ + wc0;

    for (int k0 = 0; k0 < IN_; k0 += 32) {
        __syncthreads();
        float4 ux0 = *(const float4*)(xg + k0);
        float4 ux1 = *(const float4*)(xg + k0 + 4);
        float4 uw0 = *(const float4*)(Wg + (size_t)k0 * OUT_);
        float4 uw1 = *(const float4*)(Wg + (size_t)k0 * OUT_ + 4);
        xT[(xk0 + 0) * 68 + xr] = ux0.x;
        xT[(xk0 + 1) * 68 + xr] = ux0.y;
        xT[(xk0 + 2) * 68 + xr] = ux0.z;
        xT[(xk0 + 3) * 68 + xr] = ux0.w;
        xT[(xk0 + 4) * 68 + xr] = ux1.x;
        xT[(xk0 + 5) * 68 + xr] = ux1.y;
        xT[(xk0 + 6) * 68 + xr] = ux1.z;
        xT[(xk0 + 7) * 68 + xr] = ux1.w;
        *(float4*)&Wl[wk * 68 + wc0]     = uw0;
        *(float4*)&Wl[wk * 68 + wc0 + 4] = uw1;
        __syncthreads();
#pragma unroll 8
        for (int kk = 0; kk < 32; kk++) {
            float4 a = *(const float4*)&xT[kk * 68 + tr * 4];
            float4 b = *(const float4*)&Wl[kk * 68 + tc * 4];
            acc[0][0] += a.x * b.x; acc[0][1] += a.x * b.y; acc[0][2] += a.x * b.z; acc[0][3] += a.x * b.w;
            acc[1][0] += a.y * b.x; acc[1][1] += a.y * b.y; acc[1][2] += a.y * b.z; acc[1][3] += a.y * b.w;
            acc[2][0] += a.z * b.x; acc[2][1] += a.z * b.y; acc[2][2] += a.z * b.z; acc[2][3] += a.z * b.w;
            acc[3][0] += a.w * b.x; acc[3][1] += a.w * b.y; acc[3][2] += a.w * b.z; acc[3][3] += a.w * b.w;
        }
    }
    float* og = Wh + ((size_t)h * N_ + n0) * OUT_;
#pragma unroll
    for (int i = 0; i < 4; i++) {
        float4 v = make_float4(acc[i][0], acc[i][1], acc[i][2], acc[i][3]);
        *(float4*)&og[(tr * 4 + i) * OUT_ + tc * 4] = v;
    }
}

// ---------- kernel 3: f1/f2 row dots
__global__ __launch_bounds__(256) void f_vec(const float* __restrict__ Wh,
                                             const float* __restrict__ a1,
                                             const float* __restrict__ a2,
                                             float* __restrict__ f1,
                                             float* __restrict__ f2) {
    size_t g = (size_t)blockIdx.x * 256 + threadIdx.x;
    int lane = (int)(g & 63);
    size_t row = g >> 6;               // h*N + n
    int h = (int)(row >> 12);
    float w = Wh[row * OUT_ + lane];
    float v1 = w * a1[h * OUT_ + lane];
    float v2 = w * a2[h * OUT_ + lane];
#pragma unroll
    for (int s = 32; s > 0; s >>= 1) {
        v1 += __shfl_xor(v1, s, 64);
        v2 += __shfl_xor(v2, s, 64);
    }
    if (lane == 0) { f1[row] = v1; f2[row] = v2; }
}

// ---------- kernel 4: transpose+split Wh -> WhhT/WhlT [h][o][n] bf16 (B-operand layout)
__global__ __launch_bounds__(256) void prep_whT(const float* __restrict__ Wh,
                                                uint16_t* __restrict__ WhhT,
                                                uint16_t* __restrict__ WhlT) {
    __shared__ float T[64 * 68];
    const int t  = threadIdx.x;
    const int h  = blockIdx.y;
    const int n0 = blockIdx.x * 64;
    {
        int ni = t >> 2, os = (t & 3) * 16;
        const float* src = Wh + ((size_t)h * N_ + n0 + ni) * OUT_ + os;
        float4 v0 = ((const float4*)src)[0];
        float4 v1 = ((const float4*)src)[1];
        float4 v2 = ((const float4*)src)[2];
        float4 v3 = ((const float4*)src)[3];
        *(float4*)&T[ni * 68 + os + 0]  = v0;
        *(float4*)&T[ni * 68 + os + 4]  = v1;
        *(float4*)&T[ni * 68 + os + 8]  = v2;
        *(float4*)&T[ni * 68 + os + 12] = v3;
    }
    __syncthreads();
    int o = t >> 2, ns = (t & 3) * 16;
    uint32_t ph[8], pl[8];
#pragma unroll
    for (int k = 0; k < 8; k++) {
        float v0 = T[(ns + 2 * k) * 68 + o];
        float v1 = T[(ns + 2 * k + 1) * 68 + o];
        float h0, h1, d0, d1;
        ph[k] = rne_pack2(v0, v1, h0, h1);
        pl[k] = rne_pack2(v0 - h0, v1 - h1, d0, d1);
    }
    size_t dst = ((size_t)h * OUT_ + o) * N_ + n0 + ns;
    *(uint4*)&WhhT[dst]     = make_uint4(ph[0], ph[1], ph[2], ph[3]);
    *(uint4*)&WhhT[dst + 8] = make_uint4(ph[4], ph[5], ph[6], ph[7]);
    *(uint4*)&WhlT[dst]     = make_uint4(pl[0], pl[1], pl[2], pl[3]);
    *(uint4*)&WhlT[dst + 8] = make_uint4(pl[4], pl[5], pl[6], pl[7]);
}

// ---------- kernel 5: masked softmax (unnormalized) + PV via MFMA.
// 64 rows x one head per block. P bf16 (RNE), Wh bf16 hi+lo split (fp32-exact).
__global__ __launch_bounds__(256, 4) void gat_main(const unsigned long long* __restrict__ bitsT,
                                                   const uint16_t* __restrict__ WhhT,
                                                   const uint16_t* __restrict__ WhlT,
                                                   const float* __restrict__ f1,
                                                   const float* __restrict__ f2,
                                                   float* __restrict__ out) {
    __shared__ __align__(16) uint16_t Ps[64 * 72];   // P [r][m], stride 72 (2-way banks only)
    __shared__ __align__(16) uint16_t Bh[64 * 72];   // Wh hi [o][k]
    __shared__ __align__(16) uint16_t Bl[64 * 72];   // Wh lo [o][k]
    __shared__ float Ls[64];
    const int t  = threadIdx.x;
    const int h  = blockIdx.y;
    const int n0 = blockIdx.x * 64;
    const int l  = t & 63, w = t >> 6;
    const int p  = l & 15, q = l >> 4;
    const int ra = t >> 2, ms = (t & 3) * 16;        // phase A: row, m-offset
    const int so = t >> 3, ss = (t & 7) * 8;         // staging: o-row, k-segment

    const float f1r = f1[(size_t)h * N_ + n0 + ra];
    const float* f2base = f2 + (size_t)h * N_;
    const uint16_t* sh = WhhT + ((size_t)h * OUT_ + so) * N_ + ss;
    const uint16_t* sl = WhlT + ((size_t)h * OUT_ + so) * N_ + ss;

    float Lp = 0.f;
    f32x4 acc[4];
#pragma unroll
    for (int rt = 0; rt < 4; rt++) acc[rt] = (f32x4){0.f, 0.f, 0.f, 0.f};

    for (int chunk = 0; chunk < 64; chunk++) {
        const int m0 = chunk * 64;
        __syncthreads();   // previous phase B done with Ps/Bh/Bl
        // stage B tiles (hi/lo): 64 o-rows x 64 k, k-contiguous
        {
            uint4 h0 = *(const uint4*)(sh + m0);
            uint4 h1 = *(const uint4*)(sh + (size_t)32 * N_ + m0);
            uint4 l0 = *(const uint4*)(sl + m0);
            uint4 l1 = *(const uint4*)(sl + (size_t)32 * N_ + m0);
            *(uint4*)&Bh[so * 72 + ss]        = h0;
            *(uint4*)&Bh[(so + 32) * 72 + ss] = h1;
            *(uint4*)&Bl[so * 72 + ss]        = l0;
            *(uint4*)&Bl[(so + 32) * 72 + ss] = l1;
        }
        // phase A: P[ra][ms..ms+16) = mask ? exp(leakyrelu(f1+f2)) : 0, bf16 RNE
        {
            unsigned long long word = bitsT[(size_t)chunk * N_ + n0 + ra];
            uint32_t bits16 = (uint32_t)(word >> ms) & 0xffffu;
            const float* f2p = f2base + m0 + ms;
            float pv[16];
#pragma unroll
            for (int j4 = 0; j4 < 4; j4++) {
                float4 fv = *(const float4*)(f2p + j4 * 4);
                float fs[4] = {fv.x, fv.y, fv.z, fv.w};
#pragma unroll
                for (int jj = 0; jj < 4; jj++) {
                    int j = j4 * 4 + jj;
                    float s = f1r + fs[jj];
                    float e = fmaxf(s, ALPHA_ * s);
                    float ex = __expf(e);
                    pv[j] = ((bits16 >> j) & 1u) ? ex : 0.f;
                }
            }
            uint32_t pk[8];
#pragma unroll
            for (int k = 0; k < 8; k++) {
                float r0, r1;
                pk[k] = rne_pack2(pv[2 * k], pv[2 * k + 1], r0, r1);
                Lp += r0 + r1;   // denominator from the SAME rounded values
            }
            uint16_t* pd = &Ps[ra * 72 + ms];
            *(uint4*)pd       = make_uint4(pk[0], pk[1], pk[2], pk[3]);
            *(uint4*)(pd + 8) = make_uint4(pk[4], pk[5], pk[6], pk[7]);
        }
        __syncthreads();   // Ps/Bh/Bl visible
        // phase B: wave w owns output cols [16w,16w+16). A=P[r][k], B=Wt[o][k].
#pragma unroll
        for (int k0 = 0; k0 < 2; k0++) {
            short8 bh = *(const short8*)&Bh[(w * 16 + p) * 72 + q * 8 + k0 * 32];
            short8 bl = *(const short8*)&Bl[(w * 16 + p) * 72 + q * 8 + k0 * 32];
#pragma unroll
            for (int rt = 0; rt < 4; rt++) {
                short8 af = *(const short8*)&Ps[(rt * 16 + p) * 72 + q * 8 + k0 * 32];
                acc[rt] = __builtin_amdgcn_mfma_f32_16x16x32_bf16(af, bh, acc[rt], 0, 0, 0);
                acc[rt] = __builtin_amdgcn_mfma_f32_16x16x32_bf16(af, bl, acc[rt], 0, 0, 0);
            }
        }
    }
    // denominator: reduce Lp over the 4 lanes sharing row ra (lanes l, l^1, l^2)
    {
        float v = Lp;
        v += __shfl_xor(v, 1, 64);
        v += __shfl_xor(v, 2, 64);
        if ((t & 3) == 0) Ls[ra] = v;
    }
    __syncthreads();
    // epilogue: C/D layout col=lane&15, row=(lane>>4)*4+reg (m89-verified)
#pragma unroll
    for (int rt = 0; rt < 4; rt++) {
#pragma unroll
        for (int reg = 0; reg < 4; reg++) {
            int row = rt * 16 + q * 4 + reg;
            float invL = 1.0f / Ls[row];
            out[(size_t)(n0 + row) * (H_ * OUT_) + h * OUT_ + w * 16 + p] = acc[rt][reg] * invL;
        }
    }
}

extern "C" void kernel_launch(void* const* d_in, const int* in_sizes, int n_in,
                              void* d_out, int out_size, void* d_ws, size_t ws_size,
                              hipStream_t stream) {
    const float* x   = nullptr;
    const int*   adj = nullptr;
    const float* W   = nullptr;
    const float* a1  = nullptr;
    const float* a2  = nullptr;
    for (int i = 0; i < n_in; i++) {
        long long sz = in_sizes[i];
        if      (sz == (long long)N_ * IN_)        x   = (const float*)d_in[i];
        else if (sz == (long long)N_ * N_)         adj = (const int*)d_in[i];
        else if (sz == (long long)H_ * IN_ * OUT_) W   = (const float*)d_in[i];
        else if (sz == (long long)H_ * OUT_) {
            if (!a1) a1 = (const float*)d_in[i];
            else     a2 = (const float*)d_in[i];
        }
    }
    if (!x)   x   = (const float*)d_in[0];
    if (!adj) adj = (const int*)d_in[1];
    if (!W)   W   = (const float*)d_in[2];
    if (!a1)  a1  = (const float*)d_in[3];
    if (!a2)  a2  = (const float*)d_in[4];
    float* out = (float*)d_out;

    char* ws = (char*)d_ws;
    unsigned long long* bitsT = (unsigned long long*)ws;                 // 2 MB
    float* Wh      = (float*)(ws + (2u << 20));                          // 8 MB
    float* f1      = (float*)(ws + (10u << 20));                         // 128 KB
    float* f2      = (float*)(ws + (10u << 20) + (128u << 10));          // 128 KB
    uint16_t* WhhT = (uint16_t*)(ws + (10u << 20) + (256u << 10));       // 4 MB
    uint16_t* WhlT = (uint16_t*)(ws + (14u << 20) + (256u << 10));       // 4 MB

    pack_adj<<<(N_ * (size_t)N_) / 256, 256, 0, stream>>>(adj, bitsT);
    wh_gemm<<<dim3(N_ / 64, H_), 256, 0, stream>>>(x, W, Wh);
    f_vec<<<(H_ * N_ * 64) / 256, 256, 0, stream>>>(Wh, a1, a2, f1, f2);
    prep_whT<<<dim3(N_ / 64, H_), 256, 0, stream>>>(Wh, WhhT, WhlT);
    gat_main<<<dim3(N_ / 64, H_), 256, 0, stream>>>(bitsT, WhhT, WhlT, f1, f2, out);
}

// Round 7
// 212.662 us; speedup vs baseline: 1.9663x; 1.2286x over previous
//
#include <hip/hip_runtime.h>
#include <hip/hip_bf16.h>
#include <stdint.h>

// N=4096, IN=512, OUT=64, H=8. Inputs (fp32): x, adj(int32), W, a1, a2. Output fp32[N, H*OUT].
// ws: bitsT 2MB @0 | WhhT 4MB @2M | f1 @6M | f2 @6M+128K | Lpart @6.25M |
//     op1 8MB @6.5M (overlays xh/xl after wh_mfma) | xh 4MB @6.5M | xl 4MB @10.5M |
//     WTh 512K @14.5M | WTl 512K @15M  => max live 15.5 MB

constexpr int N_ = 4096, IN_ = 512, OUT_ = 64, H_ = 8;
constexpr float ALPHA_ = 0.2f;

typedef __attribute__((ext_vector_type(8))) short short8;
typedef __attribute__((ext_vector_type(4))) float f32x4;

__device__ __forceinline__ uint32_t rne_pack2(float a, float b, float& ra, float& rb) {
    uint32_t ua = __float_as_uint(a); ua += 0x7fffu + ((ua >> 16) & 1u); ua >>= 16;
    uint32_t ub = __float_as_uint(b); ub += 0x7fffu + ((ub >> 16) & 1u); ub >>= 16;
    ra = __uint_as_float(ua << 16);
    rb = __uint_as_float(ub << 16);
    return ua | (ub << 16);
}

// ---------- pack adj -> transposed bitmask bitsT[c*N + n], bit i = adj[n][c*64+i]
__global__ __launch_bounds__(256) void pack_adj(const int* __restrict__ adj,
                                                unsigned long long* __restrict__ bitsT) {
    size_t g = (size_t)blockIdx.x * 256 + threadIdx.x;   // g = n*4096 + m
    int v = adj[g];
    unsigned long long m = __ballot(v != 0);
    if ((threadIdx.x & 63) == 0) {
        int n = (int)(g >> 12);
        int c = (int)((g >> 6) & 63);
        bitsT[(size_t)c * N_ + n] = m;
    }
}

// ---------- x fp32 -> bf16 hi/lo, same [n][k] layout
__global__ __launch_bounds__(256) void split_x(const float* __restrict__ x,
                                               uint16_t* __restrict__ xh,
                                               uint16_t* __restrict__ xl) {
    size_t g = ((size_t)blockIdx.x * 256 + threadIdx.x) * 8;
    float4 v0 = *(const float4*)(x + g);
    float4 v1 = *(const float4*)(x + g + 4);
    float v[8] = {v0.x, v0.y, v0.z, v0.w, v1.x, v1.y, v1.z, v1.w};
    uint32_t ph[4], pl[4];
#pragma unroll
    for (int i = 0; i < 4; i++) {
        float h0, h1, d0, d1;
        ph[i] = rne_pack2(v[2 * i], v[2 * i + 1], h0, h1);
        pl[i] = rne_pack2(v[2 * i] - h0, v[2 * i + 1] - h1, d0, d1);
    }
    *(uint4*)(xh + g) = make_uint4(ph[0], ph[1], ph[2], ph[3]);
    *(uint4*)(xl + g) = make_uint4(pl[0], pl[1], pl[2], pl[3]);
}

// ---------- W [h][k][o] fp32 -> WT hi/lo bf16 [h][o][k] (B-operand layout)
__global__ __launch_bounds__(256) void split_wT(const float* __restrict__ W,
                                                uint16_t* __restrict__ WTh,
                                                uint16_t* __restrict__ WTl) {
    __shared__ float T[64 * 68];
    const int t  = threadIdx.x;
    const int kb = blockIdx.x;   // 0..7
    const int h  = blockIdx.y;
    {
        int kk = t >> 2, os = (t & 3) * 16;
        const float* src = W + ((size_t)h * IN_ + kb * 64 + kk) * OUT_ + os;
#pragma unroll
        for (int j = 0; j < 4; j++)
            *(float4*)&T[kk * 68 + os + j * 4] = *(const float4*)(src + j * 4);
    }
    __syncthreads();
    int o = t >> 2, ks = (t & 3) * 16;
    uint32_t ph[8], pl[8];
#pragma unroll
    for (int i = 0; i < 8; i++) {
        float va = T[(ks + 2 * i) * 68 + o], vb = T[(ks + 2 * i + 1) * 68 + o];
        float h0, h1, d0, d1;
        ph[i] = rne_pack2(va, vb, h0, h1);
        pl[i] = rne_pack2(va - h0, vb - h1, d0, d1);
    }
    size_t dst = ((size_t)h * OUT_ + o) * IN_ + kb * 64 + ks;
    *(uint4*)&WTh[dst]     = make_uint4(ph[0], ph[1], ph[2], ph[3]);
    *(uint4*)&WTh[dst + 8] = make_uint4(ph[4], ph[5], ph[6], ph[7]);
    *(uint4*)&WTl[dst]     = make_uint4(pl[0], pl[1], pl[2], pl[3]);
    *(uint4*)&WTl[dst + 8] = make_uint4(pl[4], pl[5], pl[6], pl[7]);
}

// ---------- Wh = x@W via MFMA (hi/lo 3-product, fp32-accurate); fused epilogue:
// f1/f2 row dots + WhhT bf16 [h][o][n] for gat_main's B operand.
__global__ __launch_bounds__(256) void wh_mfma(const uint16_t* __restrict__ xh,
                                               const uint16_t* __restrict__ xl,
                                               const uint16_t* __restrict__ WTh,
                                               const uint16_t* __restrict__ WTl,
                                               const float* __restrict__ a1,
                                               const float* __restrict__ a2,
                                               uint16_t* __restrict__ WhhT,
                                               float* __restrict__ f1,
                                               float* __restrict__ f2) {
    __shared__ __align__(16) char ldsbuf[4 * 64 * 72 * 2];   // 36864 B
    uint16_t* Ah = (uint16_t*)ldsbuf;
    uint16_t* Al = Ah + 64 * 72;
    uint16_t* Bh = Al + 64 * 72;
    uint16_t* Bl = Bh + 64 * 72;
    const int t  = threadIdx.x;
    const int h  = blockIdx.y;
    const int n0 = blockIdx.x * 64;
    const int l  = t & 63, w = t >> 6;
    const int p  = l & 15, q = l >> 4;
    const int sr = t >> 2, sc = (t & 3) * 16;

    f32x4 acc[4];
#pragma unroll
    for (int rt = 0; rt < 4; rt++) acc[rt] = (f32x4){0.f, 0.f, 0.f, 0.f};

    const uint16_t* gxh = xh + (size_t)(n0 + sr) * IN_ + sc;
    const uint16_t* gxl = xl + (size_t)(n0 + sr) * IN_ + sc;
    const uint16_t* gbh = WTh + ((size_t)h * OUT_ + sr) * IN_ + sc;
    const uint16_t* gbl = WTl + ((size_t)h * OUT_ + sr) * IN_ + sc;

    for (int kt = 0; kt < 8; kt++) {
        __syncthreads();
        uint4 a0 = *(const uint4*)(gxh + kt * 64);
        uint4 a1v = *(const uint4*)(gxh + kt * 64 + 8);
        uint4 b0 = *(const uint4*)(gxl + kt * 64);
        uint4 b1 = *(const uint4*)(gxl + kt * 64 + 8);
        uint4 c0 = *(const uint4*)(gbh + kt * 64);
        uint4 c1 = *(const uint4*)(gbh + kt * 64 + 8);
        uint4 d0 = *(const uint4*)(gbl + kt * 64);
        uint4 d1 = *(const uint4*)(gbl + kt * 64 + 8);
        *(uint4*)&Ah[sr * 72 + sc]     = a0;
        *(uint4*)&Ah[sr * 72 + sc + 8] = a1v;
        *(uint4*)&Al[sr * 72 + sc]     = b0;
        *(uint4*)&Al[sr * 72 + sc + 8] = b1;
        *(uint4*)&Bh[sr * 72 + sc]     = c0;
        *(uint4*)&Bh[sr * 72 + sc + 8] = c1;
        *(uint4*)&Bl[sr * 72 + sc]     = d0;
        *(uint4*)&Bl[sr * 72 + sc + 8] = d1;
        __syncthreads();
#pragma unroll
        for (int k0 = 0; k0 < 2; k0++) {
            short8 bhf = *(const short8*)&Bh[(w * 16 + p) * 72 + q * 8 + k0 * 32];
            short8 blf = *(const short8*)&Bl[(w * 16 + p) * 72 + q * 8 + k0 * 32];
#pragma unroll
            for (int rt = 0; rt < 4; rt++) {
                short8 ahf = *(const short8*)&Ah[(rt * 16 + p) * 72 + q * 8 + k0 * 32];
                short8 alf = *(const short8*)&Al[(rt * 16 + p) * 72 + q * 8 + k0 * 32];
                acc[rt] = __builtin_amdgcn_mfma_f32_16x16x32_bf16(ahf, bhf, acc[rt], 0, 0, 0);
                acc[rt] = __builtin_amdgcn_mfma_f32_16x16x32_bf16(alf, bhf, acc[rt], 0, 0, 0);
                acc[rt] = __builtin_amdgcn_mfma_f32_16x16x32_bf16(ahf, blf, acc[rt], 0, 0, 0);
            }
        }
    }
    __syncthreads();
    float* Whs = (float*)ldsbuf;   // 64*68 floats = 17408 B (fits in Ah+Al region)
#pragma unroll
    for (int rt = 0; rt < 4; rt++)
#pragma unroll
        for (int reg = 0; reg < 4; reg++)
            Whs[(rt * 16 + q * 4 + reg) * 68 + w * 16 + p] = acc[rt][reg];
    __syncthreads();
    {   // f1/f2: thread group of 4 covers one row
        int r = t >> 2, og = (t & 3) * 16;
        float s1 = 0.f, s2 = 0.f;
#pragma unroll
        for (int j = 0; j < 4; j++) {
            float4 wv = *(const float4*)&Whs[r * 68 + og + j * 4];
            float4 av = *(const float4*)(a1 + h * OUT_ + og + j * 4);
            float4 bv = *(const float4*)(a2 + h * OUT_ + og + j * 4);
            s1 += wv.x * av.x + wv.y * av.y + wv.z * av.z + wv.w * av.w;
            s2 += wv.x * bv.x + wv.y * bv.y + wv.z * bv.z + wv.w * bv.w;
        }
        s1 += __shfl_xor(s1, 1, 64); s1 += __shfl_xor(s1, 2, 64);
        s2 += __shfl_xor(s2, 1, 64); s2 += __shfl_xor(s2, 2, 64);
        if ((t & 3) == 0) {
            f1[(size_t)h * N_ + n0 + r] = s1;
            f2[(size_t)h * N_ + n0 + r] = s2;
        }
    }
    {   // WhhT bf16 (hi only), [h][o][n]
        int o = t >> 2, ns = (t & 3) * 16;
        uint32_t ph[8];
#pragma unroll
        for (int i = 0; i < 8; i++) {
            float va = Whs[(ns + 2 * i) * 68 + o], vb = Whs[(ns + 2 * i + 1) * 68 + o];
            float h0, h1;
            ph[i] = rne_pack2(va, vb, h0, h1);
        }
        size_t dst = ((size_t)h * OUT_ + o) * N_ + n0 + ns;
        *(uint4*)&WhhT[dst]     = make_uint4(ph[0], ph[1], ph[2], ph[3]);
        *(uint4*)&WhhT[dst + 8] = make_uint4(ph[4], ph[5], ph[6], ph[7]);
    }
}

// ---------- main: P computed in-register in MFMA A-layout; B (Wh hi) via LDS.
// grid (64 rowblocks, 8 heads, 2 m-halves). Writes raw numerators + L partials.
__global__ __launch_bounds__(256, 4) void gat_main(const unsigned long long* __restrict__ bitsT,
                                                   const uint16_t* __restrict__ WhhT,
                                                   const float* __restrict__ f1,
                                                   const float* __restrict__ f2,
                                                   float* __restrict__ outNum,
                                                   float* __restrict__ op1,
                                                   float* __restrict__ Lpart) {
    __shared__ __align__(16) uint16_t Bh[64 * 72];   // 9216 B
    const int t  = threadIdx.x;
    const int h  = blockIdx.y, z = blockIdx.z;
    const int n0 = blockIdx.x * 64;
    const int l  = t & 63, w = t >> 6;
    const int p  = l & 15, q = l >> 4;
    const int sr = t >> 2, sc = (t & 3) * 16;
    const int row = w * 16 + p;                      // this lane's P row (A-frag m)

    const float f1v = f1[(size_t)h * N_ + n0 + row];
    const float* f2b = f2 + (size_t)h * N_;
    const uint16_t* gb = WhhT + ((size_t)h * OUT_ + sr) * N_ + sc;

    float Lp = 0.f;
    f32x4 acc[4];
#pragma unroll
    for (int ct = 0; ct < 4; ct++) acc[ct] = (f32x4){0.f, 0.f, 0.f, 0.f};

    for (int cc = 0; cc < 32; cc++) {
        const int chunk = z * 32 + cc;
        const int m0 = chunk * 64;
        __syncthreads();   // prev MFMA reads done with Bh
        uint4 b0 = *(const uint4*)(gb + m0);
        uint4 b1 = *(const uint4*)(gb + m0 + 8);
        *(uint4*)&Bh[sr * 72 + sc]     = b0;
        *(uint4*)&Bh[sr * 72 + sc + 8] = b1;
        unsigned long long word = bitsT[(size_t)chunk * N_ + n0 + row];
        __syncthreads();   // Bh visible
#pragma unroll
        for (int k0 = 0; k0 < 2; k0++) {
            const float* fp = f2b + m0 + k0 * 32 + q * 8;
            float4 fv0 = *(const float4*)fp;
            float4 fv1 = *(const float4*)(fp + 4);
            float fs[8] = {fv0.x, fv0.y, fv0.z, fv0.w, fv1.x, fv1.y, fv1.z, fv1.w};
            uint32_t bits8 = (uint32_t)(word >> (k0 * 32 + q * 8)) & 0xffu;
            float pv[8];
#pragma unroll
            for (int j = 0; j < 8; j++) {
                float s = f1v + fs[j];
                float e = fmaxf(s, ALPHA_ * s);
                float ex = __expf(e);
                pv[j] = ((bits8 >> j) & 1u) ? ex : 0.f;
            }
            union { short8 s8; uint32_t u[4]; } af;
#pragma unroll
            for (int i = 0; i < 4; i++) {
                float r0, r1;
                af.u[i] = rne_pack2(pv[2 * i], pv[2 * i + 1], r0, r1);
                Lp += r0 + r1;   // denominator from the SAME rounded values
            }
#pragma unroll
            for (int ct = 0; ct < 4; ct++) {
                short8 bhf = *(const short8*)&Bh[(ct * 16 + p) * 72 + q * 8 + k0 * 32];
                acc[ct] = __builtin_amdgcn_mfma_f32_16x16x32_bf16(af.s8, bhf, acc[ct], 0, 0, 0);
            }
        }
    }
    // reduce Lp across the 4 q-lanes sharing this row
    float Ls = Lp;
    Ls += __shfl_xor(Ls, 16, 64);
    Ls += __shfl_xor(Ls, 32, 64);
    if (q == 0) Lpart[((size_t)z * 8 + h) * N_ + n0 + row] = Ls;
    // raw numerators; C/D layout col=lane&15, row=(lane>>4)*4+reg
    float* dst = (z == 0) ? outNum : op1;
#pragma unroll
    for (int ct = 0; ct < 4; ct++)
#pragma unroll
        for (int reg = 0; reg < 4; reg++) {
            int rr = w * 16 + q * 4 + reg;
            dst[(size_t)(n0 + rr) * (H_ * OUT_) + h * OUT_ + ct * 16 + p] = acc[ct][reg];
        }
}

// ---------- combine halves + normalize
__global__ __launch_bounds__(256) void combine(float* __restrict__ outb,
                                               const float* __restrict__ op1,
                                               const float* __restrict__ Lpart) {
    size_t g = (size_t)blockIdx.x * 256 + threadIdx.x;   // float4 index
    int n = (int)(g >> 7);
    int c = (int)(g & 127);
    int h = c >> 4;
    float4 o0 = ((const float4*)outb)[g];
    float4 o1 = ((const float4*)op1)[g];
    float L = Lpart[(size_t)h * N_ + n] + Lpart[(size_t)(8 + h) * N_ + n];
    float inv = 1.f / L;
    ((float4*)outb)[g] = make_float4((o0.x + o1.x) * inv, (o0.y + o1.y) * inv,
                                     (o0.z + o1.z) * inv, (o0.w + o1.w) * inv);
}

extern "C" void kernel_launch(void* const* d_in, const int* in_sizes, int n_in,
                              void* d_out, int out_size, void* d_ws, size_t ws_size,
                              hipStream_t stream) {
    const float* x   = nullptr;
    const int*   adj = nullptr;
    const float* W   = nullptr;
    const float* a1  = nullptr;
    const float* a2  = nullptr;
    for (int i = 0; i < n_in; i++) {
        long long sz = in_sizes[i];
        if      (sz == (long long)N_ * IN_)        x   = (const float*)d_in[i];
        else if (sz == (long long)N_ * N_)         adj = (const int*)d_in[i];
        else if (sz == (long long)H_ * IN_ * OUT_) W   = (const float*)d_in[i];
        else if (sz == (long long)H_ * OUT_) {
            if (!a1) a1 = (const float*)d_in[i];
            else     a2 = (const float*)d_in[i];
        }
    }
    if (!x)   x   = (const float*)d_in[0];
    if (!adj) adj = (const int*)d_in[1];
    if (!W)   W   = (const float*)d_in[2];
    if (!a1)  a1  = (const float*)d_in[3];
    if (!a2)  a2  = (const float*)d_in[4];
    float* out = (float*)d_out;

    char* ws = (char*)d_ws;
    unsigned long long* bitsT = (unsigned long long*)ws;                     // 2 MB @0
    uint16_t* WhhT = (uint16_t*)(ws + (2u  << 20));                          // 4 MB @2M
    float* f1      = (float*)   (ws + (6u  << 20));                          // 128 KB
    float* f2      = (float*)   (ws + (6u  << 20) + (128u << 10));           // 128 KB
    float* Lpart   = (float*)   (ws + (6u  << 20) + (256u << 10));           // 256 KB
    float* op1     = (float*)   (ws + (6u  << 20) + (512u << 10));           // 8 MB (phase 2)
    uint16_t* xh   = (uint16_t*)(ws + (6u  << 20) + (512u << 10));           // 4 MB (phase 1, overlays op1)
    uint16_t* xl   = (uint16_t*)(ws + (10u << 20) + (512u << 10));           // 4 MB (phase 1)
    uint16_t* WTh  = (uint16_t*)(ws + (14u << 20) + (512u << 10));           // 512 KB (phase 1)
    uint16_t* WTl  = (uint16_t*)(ws + (15u << 20));                          // 512 KB (phase 1)

    pack_adj<<<(N_ * (size_t)N_) / 256, 256, 0, stream>>>(adj, bitsT);
    split_x<<<(N_ * IN_) / (256 * 8), 256, 0, stream>>>(x, xh, xl);
    split_wT<<<dim3(IN_ / 64, H_), 256, 0, stream>>>(W, WTh, WTl);
    wh_mfma<<<dim3(N_ / 64, H_), 256, 0, stream>>>(xh, xl, WTh, WTl, a1, a2, WhhT, f1, f2);
    gat_main<<<dim3(N_ / 64, H_, 2), 256, 0, stream>>>(bitsT, WhhT, f1, f2, out, op1, Lpart);
    combine<<<(N_ * H_ * OUT_) / (256 * 4), 256, 0, stream>>>(out, op1, Lpart);
}